// Round 1
// baseline (1361.744 us; speedup 1.0000x reference)
//
#include <hip/hip_runtime.h>
#include <hip/hip_bf16.h>

// TreeHopNode: h = q - rep + (per-head MLP(sigmoid(Qh*Kh/16)*Vh)) @ Ws
// N=65536, E=1024, H=4, G=256, MLP=256. All GEMMs in bf16 MFMA, f32 accum.
//
// Pipeline:
//   1. cvt_bf16        : q, rep -> bf16
//   2. prep_weights    : Wq/Wk/Wv/Ws/W1/W2 -> transposed ([col][k]) bf16
//   3. qkvz_kernel     : z = sigmoid(qWq * repWk / 16) * repWv   (3-pass, LDS stash)
//   4. gemm (K=256)    : h1 = relu(z @ W1 + b1)   per head
//   5. gemm (K=256)    : ug = h1 @ W2 + b2        per head
//   6. gemm (K=1024)   : out = q - rep + ug @ Ws  (f32 epilogue)

#define BM 128
#define BN 128
#define BK 64

typedef __attribute__((ext_vector_type(8))) short bf16x8;
typedef __attribute__((ext_vector_type(4))) float f32x4;
typedef __attribute__((ext_vector_type(4))) short short4v;

static __device__ __forceinline__ short f2b(float x) {
  __hip_bfloat16 h = __float2bfloat16(x);
  return __builtin_bit_cast(short, h);
}
static __device__ __forceinline__ float b2f(short s) {
  unsigned u = ((unsigned)(unsigned short)s) << 16;
  return __builtin_bit_cast(float, u);
}

// ---- async global->LDS staging of a [128 rows x 64 k] bf16 tile ----
// LDS layout: linear [128][BK] shorts (global_load_lds writes base + lane*16B,
// so LDS must be linear in lane order: lane l -> row r0+l/8, bytes (l&7)*16).
static __device__ __forceinline__ void stage_tile(
    const short* __restrict__ g, int ld, short* lds, int wave, int lane)
{
  const short* gl = g + (long)(lane >> 3) * ld + ((lane & 7) << 3);
  #pragma unroll
  for (int i = 0; i < 4; ++i) {
    const int r0 = (wave * 4 + i) * 8;   // 8 rows per instruction, 4 insts/wave
    __builtin_amdgcn_global_load_lds(
        (const __attribute__((address_space(1))) void*)(gl + (long)r0 * ld),
        (__attribute__((address_space(3))) void*)(lds + r0 * BK),
        16, 0, 0);
  }
}

// MFMA 16x16x32 fragment from LDS tile [.][BK]: lane l -> row r0+(l&15),
// k = kk + (l>>4)*8 .. +8 (contiguous -> one ds_read_b128)
static __device__ __forceinline__ bf16x8 frag(const short* lds, int r0, int kk, int lane) {
  return *(const bf16x8*)(lds + (r0 + (lane & 15)) * BK + kk + ((lane >> 4) << 3));
}

// ---------------- convert f32 -> bf16, vectorized ----------------
__global__ void cvt_bf16(const float* __restrict__ in, short* __restrict__ out, long n) {
  long i = ((long)blockIdx.x * blockDim.x + threadIdx.x) * 4;
  const long stride = (long)gridDim.x * blockDim.x * 4;
  for (; i < n; i += stride) {
    float4 v = *(const float4*)(in + i);
    short4v o = { f2b(v.x), f2b(v.y), f2b(v.z), f2b(v.w) };
    *(short4v*)(out + i) = o;
  }
}

// ---------------- transpose + convert weights ----------------
// dst[c][r] = bf16(src[r][c]); jobs: 0..2 Wq/Wk/Wv (1024x1024), 3 Ws,
// 4..7 W1 heads (256x256), 8..11 W2 heads.
__global__ void prep_weights(
    const float* __restrict__ Wq, const float* __restrict__ Wk, const float* __restrict__ Wv,
    const float* __restrict__ W1, const float* __restrict__ W2, const float* __restrict__ Ws,
    short* __restrict__ wqt, short* __restrict__ wkt, short* __restrict__ wvt,
    short* __restrict__ w1t, short* __restrict__ w2t, short* __restrict__ wst)
{
  const int job = blockIdx.z;
  const float* src; short* dst; int R, C;
  if (job < 3)       { src = (job==0)?Wq:((job==1)?Wk:Wv); dst = (job==0)?wqt:((job==1)?wkt:wvt); R = 1024; C = 1024; }
  else if (job == 3) { src = Ws; dst = wst; R = 1024; C = 1024; }
  else if (job < 8)  { int h = job-4; src = W1 + h*65536; dst = w1t + h*65536; R = 256; C = 256; }
  else               { int h = job-8; src = W2 + h*65536; dst = w2t + h*65536; R = 256; C = 256; }
  const int c0 = blockIdx.x * 32, r0 = blockIdx.y * 32;
  if (c0 >= C || r0 >= R) return;
  __shared__ float t[32][33];
  for (int i = threadIdx.y; i < 32; i += 8)
    t[i][threadIdx.x] = src[(long)(r0 + i) * C + c0 + threadIdx.x];
  __syncthreads();
  for (int i = threadIdx.y; i < 32; i += 8)
    dst[(long)(c0 + i) * R + r0 + threadIdx.x] = f2b(t[threadIdx.x][i]);
}

// ---------------- fused QKV + sigmoid gate -> z ----------------
// 3 sequential K=1024 passes per 128x128 tile; Q then gate stashed in LDS bf16.
// Per-wave 64x64 quadrant of stash is private to that wave -> no extra barriers.
__global__ __launch_bounds__(256) void qkvz_kernel(
    const short* __restrict__ qb, const short* __restrict__ rb,
    const short* __restrict__ wqt, const short* __restrict__ wkt, const short* __restrict__ wvt,
    short* __restrict__ z)
{
  __shared__ __align__(16) short lA[BM * BK];
  __shared__ __align__(16) short lB[BN * BK];
  __shared__ __align__(16) short stash[BM * BN];
  const int lane = threadIdx.x & 63, wave = threadIdx.x >> 6;
  const int wm = wave >> 1, wn = wave & 1;
  const long bm = (long)blockIdx.y * BM;
  const int  bn = blockIdx.x * BN;

  for (int pass = 0; pass < 3; ++pass) {
    const short* A  = ((pass == 0) ? qb : rb) + bm * 1024;
    const short* Bt = ((pass == 0) ? wqt : ((pass == 1) ? wkt : wvt)) + (long)bn * 1024;
    f32x4 acc[4][4] = {};
    for (int k0 = 0; k0 < 1024; k0 += BK) {
      __syncthreads();                       // prior readers of lA/lB done
      stage_tile(A  + k0, 1024, lA, wave, lane);
      stage_tile(Bt + k0, 1024, lB, wave, lane);
      __syncthreads();                       // vmcnt(0) drain -> tiles ready
      #pragma unroll
      for (int kk = 0; kk < BK; kk += 32) {
        bf16x8 af[4], bg[4];
        #pragma unroll
        for (int i = 0; i < 4; ++i) af[i] = frag(lA, wm * 64 + i * 16, kk, lane);
        #pragma unroll
        for (int j = 0; j < 4; ++j) bg[j] = frag(lB, wn * 64 + j * 16, kk, lane);
        #pragma unroll
        for (int i = 0; i < 4; ++i)
          #pragma unroll
          for (int j = 0; j < 4; ++j)
            acc[i][j] = __builtin_amdgcn_mfma_f32_16x16x32_bf16(af[i], bg[j], acc[i][j], 0, 0, 0);
      }
    }
    // elementwise epilogue; C/D layout: col=lane&15, row=(lane>>4)*4+reg (m89)
    #pragma unroll
    for (int i = 0; i < 4; ++i)
      #pragma unroll
      for (int j = 0; j < 4; ++j)
        #pragma unroll
        for (int r = 0; r < 4; ++r) {
          const int rl = wm * 64 + i * 16 + ((lane >> 4) << 2) + r;
          const int cl = wn * 64 + j * 16 + (lane & 15);
          const int sidx = rl * BN + cl;
          const float v = acc[i][j][r];
          if (pass == 0) {
            stash[sidx] = f2b(v);                       // Qh
          } else if (pass == 1) {
            const float x = b2f(stash[sidx]) * v * 0.0625f;   // Qh*Kh/sqrt(256)
            stash[sidx] = f2b(1.0f / (1.0f + __expf(-x)));    // gate
          } else {
            z[(bm + rl) * 1024 + bn + cl] = f2b(b2f(stash[sidx]) * v);  // gate*Vh
          }
        }
  }
}

// ---------------- generic 128x128-tile bf16 GEMM ----------------
// C = act(A @ Bt^T + bias); Bt stored [col][k]. blockIdx.z batches heads via
// element strides zsa/zsb/zsc/zsbias. RESID: f32 out = q - rep + acc.
template <int KDIM, bool RELU, bool BIAS, bool RESID>
__global__ __launch_bounds__(256) void gemm_bf16(
    const short* __restrict__ A, long lda, long zsa,
    const short* __restrict__ Bt, long ldb, long zsb,
    void* __restrict__ outv, long ldc, long zsc,
    const float* __restrict__ bias, long zsbias,
    const float* __restrict__ q, const float* __restrict__ rep)
{
  __shared__ __align__(16) short lA[BM * BK];
  __shared__ __align__(16) short lB[BN * BK];
  const int lane = threadIdx.x & 63, wave = threadIdx.x >> 6;
  const int wm = wave >> 1, wn = wave & 1;
  const long bm = (long)blockIdx.y * BM;
  const int  bn = blockIdx.x * BN;
  const int  zi = blockIdx.z;

  const short* Ab = A + (long)zi * zsa + bm * lda;
  const short* Bb = Bt + (long)zi * zsb + (long)bn * ldb;
  f32x4 acc[4][4] = {};
  for (int k0 = 0; k0 < KDIM; k0 += BK) {
    __syncthreads();
    stage_tile(Ab + k0, (int)lda, lA, wave, lane);
    stage_tile(Bb + k0, (int)ldb, lB, wave, lane);
    __syncthreads();
    #pragma unroll
    for (int kk = 0; kk < BK; kk += 32) {
      bf16x8 af[4], bg[4];
      #pragma unroll
      for (int i = 0; i < 4; ++i) af[i] = frag(lA, wm * 64 + i * 16, kk, lane);
      #pragma unroll
      for (int j = 0; j < 4; ++j) bg[j] = frag(lB, wn * 64 + j * 16, kk, lane);
      #pragma unroll
      for (int i = 0; i < 4; ++i)
        #pragma unroll
        for (int j = 0; j < 4; ++j)
          acc[i][j] = __builtin_amdgcn_mfma_f32_16x16x32_bf16(af[i], bg[j], acc[i][j], 0, 0, 0);
    }
  }
  #pragma unroll
  for (int i = 0; i < 4; ++i)
    #pragma unroll
    for (int j = 0; j < 4; ++j)
      #pragma unroll
      for (int r = 0; r < 4; ++r) {
        const int rl = wm * 64 + i * 16 + ((lane >> 4) << 2) + r;
        const int cl = wn * 64 + j * 16 + (lane & 15);
        float v = acc[i][j][r];
        if (BIAS) v += bias[(long)zi * zsbias + bn + cl];
        if (RELU) v = v > 0.0f ? v : 0.0f;
        const long row = bm + rl;
        if (RESID) {
          const long gi = row * ldc + bn + cl;   // ldc == 1024, full width
          ((float*)outv)[gi] = q[gi] - rep[gi] + v;
        } else {
          ((short*)outv)[(long)zi * zsc + row * ldc + bn + cl] = f2b(v);
        }
      }
}

extern "C" void kernel_launch(void* const* d_in, const int* in_sizes, int n_in,
                              void* d_out, int out_size, void* d_ws, size_t ws_size,
                              hipStream_t stream) {
  const float* q   = (const float*)d_in[0];
  const float* rep = (const float*)d_in[1];
  const float* Wq  = (const float*)d_in[2];
  const float* Wk  = (const float*)d_in[3];
  const float* Wv  = (const float*)d_in[4];
  const float* W1  = (const float*)d_in[5];
  const float* b1  = (const float*)d_in[6];
  const float* W2  = (const float*)d_in[7];
  const float* b2  = (const float*)d_in[8];
  const float* Ws  = (const float*)d_in[9];
  float* out = (float*)d_out;

  const long NE = 67108864L;   // 65536 * 1024
  char* ws = (char*)d_ws;
  short* qb  = (short*)(ws);                 // q bf16    (128 MiB)
  short* rb  = (short*)(ws + NE * 2);        // rep bf16  (128 MiB)
  short* zb  = (short*)(ws + NE * 4);        // z bf16    (128 MiB)
  char*  wp  = ws + NE * 6;
  short* wqt = (short*)(wp);                 // 2 MiB each
  short* wkt = (short*)(wp + 2097152);
  short* wvt = (short*)(wp + 4194304);
  short* wst = (short*)(wp + 6291456);
  short* w1t = (short*)(wp + 8388608);       // 512 KiB
  short* w2t = (short*)(wp + 8912896);       // 512 KiB
  short* h1b = qb;   // reuse: q bf16 dead after qkvz pass 0 usage completes
  short* ugb = rb;   // reuse: rep bf16 dead after qkvz

  cvt_bf16<<<4096, 256, 0, stream>>>(q,   qb, NE);
  cvt_bf16<<<4096, 256, 0, stream>>>(rep, rb, NE);
  prep_weights<<<dim3(32, 32, 12), dim3(32, 8), 0, stream>>>(
      Wq, Wk, Wv, W1, W2, Ws, wqt, wkt, wvt, w1t, w2t, wst);

  qkvz_kernel<<<dim3(8, 512), 256, 0, stream>>>(qb, rb, wqt, wkt, wvt, zb);

  // h1 = relu(z @ W1 + b1), per head (z = blockIdx.z)
  gemm_bf16<256, true, true, false><<<dim3(2, 512, 4), 256, 0, stream>>>(
      zb, 1024, 256, w1t, 256, 65536, h1b, 1024, 256, b1, 256, nullptr, nullptr);
  // ug = h1 @ W2 + b2, per head
  gemm_bf16<256, false, true, false><<<dim3(2, 512, 4), 256, 0, stream>>>(
      h1b, 1024, 256, w2t, 256, 65536, ugb, 1024, 256, b2, 256, nullptr, nullptr);
  // out = q - rep + ug @ Ws
  gemm_bf16<1024, false, false, true><<<dim3(8, 512, 1), 256, 0, stream>>>(
      ugb, 1024, 0, wst, 1024, 0, out, 1024, 0, nullptr, 0, q, rep);
}